// Round 16
// baseline (776.456 us; speedup 1.0000x reference)
//
#include <hip/hip_runtime.h>

#define B_ 2
#define T_ 8
#define C_ 256
#define H_ 128
#define W_ 128
#define NBT (B_*T_)
#define L_ 128
#define HEADS_ 8
#define DIM_ 32
#define C3 (3*C_)
#define SCALE_ 0.17677669529663687f
#define LOG2E_ 1.4426950408889634f
#define QSTR 104   // qkvt LDS row stride (ush): 96 cols + 8 pad (bank-spread)

typedef __bf16 bf16x8 __attribute__((ext_vector_type(8)));
typedef float f32x4 __attribute__((ext_vector_type(4)));
typedef unsigned short ush;
typedef unsigned short u16x4 __attribute__((ext_vector_type(4)));
typedef unsigned int uint_a __attribute__((may_alias));

__device__ __forceinline__ ush f2bf(float f){
  union { float f; unsigned int u; } v; v.f = f;
  unsigned int r = v.u + 0x7fffu + ((v.u >> 16) & 1u);
  return (ush)(r >> 16);
}

#if __has_builtin(__builtin_amdgcn_exp2f)
#define EXP2(x) __builtin_amdgcn_exp2f(x)
#else
#define EXP2(x) exp2f(x)
#endif

#if __has_builtin(__builtin_amdgcn_global_load_lds)
#define HAVE_GLL 1
typedef __attribute__((address_space(3))) ush lds_ush;
typedef __attribute__((address_space(1))) const ush glb_ush;
__device__ __forceinline__ void gll16(const ush* g, ush* l){
  __builtin_amdgcn_global_load_lds((glb_ush*)g, (lds_ush*)l, 16, 0, 0);
}
#endif

// ---------------- setup: weight f32->bf16 + bias*log2e (lane-contig layout) ----------------
__global__ __launch_bounds__(256) void k_setup(const float* __restrict__ wq, const float* __restrict__ wp,
                                               const float* __restrict__ rb,
                                               ush* __restrict__ wqb, ush* __restrict__ wpb,
                                               float* __restrict__ be){
  int i = blockIdx.x*256 + threadIdx.x;
  if (i < C3*C_) wqb[i] = f2bf(wq[i]);
  if (i < C_*C_) wpb[i] = f2bf(wp[i]);
  if (i < HEADS_*L_*L_){
    int col = i & (L_-1);
    int hrow = i >> 7;           // h*L + row
    int tgt = ((hrow<<4) + (col & 15))*8 + (col >> 4);
    be[tgt] = rb[i]*LOG2E_;
  }
}

// ---------------- transpose x (bt,c,l,w) -> xT[btL][l][w][c] bf16 ----------------
__global__ __launch_bounds__(256) void k_trans(const float* __restrict__ x, ush* __restrict__ xT, int bt0){
  __shared__ float tile[64*129];
  const int l   = blockIdx.x & (L_-1);
  const int btL = blockIdx.x >> 7;
  const int t = threadIdx.x;
  const float* xp = x + (size_t)(bt0 + btL)*C_*H_*W_ + (size_t)l*W_;
  ush* xo = xT + ((size_t)blockIdx.x) * W_ * C_;
  const int wI = t & (W_-1);
  const int chh = t >> 7;
  const int c2 = (t & 31)*2;
  const int wr0 = t >> 5;
  for (int cs = 0; cs < 4; ++cs){
    #pragma unroll 4
    for (int i = 0; i < 32; ++i){
      int cl = chh*32 + i;
      tile[cl*129 + wI] = xp[(size_t)(cs*64 + cl)*(H_*W_) + wI];
    }
    __syncthreads();
    #pragma unroll 4
    for (int i = 0; i < 16; ++i){
      int wr = wr0 + i*8;
      float v0 = tile[c2*129 + wr];
      float v1 = tile[(c2+1)*129 + wr];
      unsigned int pk = (unsigned int)f2bf(v0) | ((unsigned int)f2bf(v1) << 16);
      *(uint_a*)(xo + (size_t)wr*C_ + cs*64 + c2) = pk;
    }
    __syncthreads();
  }
}

// ---------------- fused QKV GEMM + attention, per (btL, w, h) ----------------
// R14's coalesced staging restored (A-direct reverted). LDS shrunk by
// single-buffering lA/lB (R1-R5's 2-barrier K-loop) + R15's proven qkvt/pT
// overlay: 61.4 KB -> 34.8 KB -> 4 blocks/CU; launch_bounds pins VGPR<=128.
__global__ __launch_bounds__(256, 4) void k_qkvattn(const ush* __restrict__ xT, const ush* __restrict__ wqb,
                                                    const float* __restrict__ bq, const float* __restrict__ biasE,
                                                    ush* __restrict__ o){
  __shared__ ush smem[17408];            // 34816 B
  int idx = blockIdx.x;
  int lo3 = idx & 7, rest = idx >> 3;
  int h = rest & 7;
  int lw = (rest >> 3)*8 + lo3;          // btL*W + w
  const int btL = lw >> 7, w = lw & (W_-1);
  const int t = threadIdx.x;
  const int lane = t & 63, wv = t >> 6;
  const int li = lane & 15, g = lane >> 4;
  ush* lA = smem;                        // GEMM: 128x64 (16384 B)
  ush* lB = smem + 8192;                 // GEMM: 96x64  (12288 B)
  ush* qkvt = smem;                      // attn: 128 x QSTR (26624 B)
  ush* pTw = smem + wv*(32*136);         // after qkvt consumed (34816 B)
  const ush* xA = xT + (size_t)btL*L_*W_*C_ + (size_t)w*C_;   // + l*(W_*C_) + c
  const int rowOff = lane >> 3;
  const int srcCl  = (lane & 7) ^ rowOff;
  f32x4 acc[2][6] = {};
  auto stage = [&](int ks){
#ifdef HAVE_GLL
    #pragma unroll
    for (int c = 0; c < 4; ++c){
      int chunk = wv*4 + c;              // 0..15
      int row = chunk*8 + rowOff;        // l: 0..127
      gll16(xA + (size_t)row*(W_*C_) + ks*64 + srcCl*8, &lA[chunk*512]);
    }
    #pragma unroll
    for (int c = 0; c < 3; ++c){
      int chunk = wv*3 + c;              // 0..11
      int row = chunk*8 + rowOff;        // 0..95
      int wr = (row >> 5)*C_ + h*DIM_ + (row & 31);
      gll16(wqb + (size_t)wr*C_ + ks*64 + srcCl*8, &lB[chunk*512]);
    }
#else
    #pragma unroll
    for (int j = 0; j < 4; ++j){
      int cid = j*256 + t;
      int row = cid >> 3, cl = cid & 7;
      int sw = ((cl ^ (row & 7)) << 3);
      *(bf16x8*)&lA[row*64 + sw] = *(const bf16x8*)&xA[(size_t)row*(W_*C_) + ks*64 + cl*8];
    }
    #pragma unroll
    for (int j = 0; j < 3; ++j){
      int cid = j*256 + t;
      int row = cid >> 3, cl = cid & 7;
      if (row < 96){
        int wr = (row >> 5)*C_ + h*DIM_ + (row & 31);
        int sw = ((cl ^ (row & 7)) << 3);
        *(bf16x8*)&lB[row*64 + sw] = *(const bf16x8*)&wqb[(size_t)wr*C_ + ks*64 + cl*8];
      }
    }
#endif
  };
  for (int ks = 0; ks < 4; ++ks){
    __syncthreads();   // previous step's lA/lB reads complete (no-op at ks=0)
    stage(ks);
    __syncthreads();   // staged data visible (barrier drains vmcnt)
    #pragma unroll
    for (int kk = 0; kk < 2; ++kk){
      bf16x8 af[2], bfr[6];
      int chunk = kk*4 + g;
      #pragma unroll
      for (int mf = 0; mf < 2; ++mf){
        int row = wv*32 + mf*16 + li;
        af[mf] = *(const bf16x8*)&lA[row*64 + ((chunk ^ (row & 7)) << 3)];
      }
      #pragma unroll
      for (int nf = 0; nf < 6; ++nf){
        int row = nf*16 + li;
        bfr[nf] = *(const bf16x8*)&lB[row*64 + ((chunk ^ (row & 7)) << 3)];
      }
      #pragma unroll
      for (int mf = 0; mf < 2; ++mf)
        #pragma unroll
        for (int nf = 0; nf < 6; ++nf)
          acc[mf][nf] = __builtin_amdgcn_mfma_f32_16x16x32_bf16(af[mf], bfr[nf], acc[mf][nf], 0, 0, 0);
    }
  }
  __syncthreads();   // final lA/lB reads done; smem free for qkvt
  // ---- epilogue: bias-add, bf16, drop into qkvt[l][0..96) ----
  float bqv[6];
  #pragma unroll
  for (int nf = 0; nf < 6; ++nf){
    int col = nf*16 + li;
    bqv[nf] = bq[(col >> 5)*C_ + h*DIM_ + (col & 31)];
  }
  #pragma unroll
  for (int mf = 0; mf < 2; ++mf)
    #pragma unroll
    for (int r = 0; r < 4; ++r){
      int m = wv*32 + mf*16 + 4*g + r;
      #pragma unroll
      for (int nf = 0; nf < 6; ++nf)
        qkvt[m*QSTR + nf*16 + li] = f2bf(acc[mf][nf][r] + bqv[nf]);
    }
  __syncthreads();
  // ---- attention (wave wv handles q-rows [wv*32, wv*32+32)) ----
  const float KS = SCALE_ * LOG2E_;
  bf16x8 kb[8];
  #pragma unroll
  for (int nf = 0; nf < 8; ++nf)
    kb[nf] = *(const bf16x8*)&qkvt[(nf*16 + li)*QSTR + DIM_ + 8*g];
  bf16x8 vb[2][4];
  #pragma unroll
  for (int nf = 0; nf < 2; ++nf)
    #pragma unroll
    for (int kk = 0; kk < 4; ++kk){
      ush tmp[8];
      #pragma unroll
      for (int j = 0; j < 8; ++j)
        tmp[j] = qkvt[(kk*32 + 8*g + j)*QSTR + 2*DIM_ + nf*16 + li];
      __builtin_memcpy(&vb[nf][kk], tmp, 16);
    }
  bf16x8 qa[2];
  #pragma unroll
  for (int mf = 0; mf < 2; ++mf)
    qa[mf] = *(const bf16x8*)&qkvt[(wv*32 + mf*16 + li)*QSTR + 8*g];
  __syncthreads();   // qkvt fully consumed into registers; pT may overwrite
  const float* bh = biasE + (size_t)h * L_ * L_;
  f32x4 s[2][8] = {};
  __builtin_amdgcn_s_setprio(1);
  #pragma unroll
  for (int mf = 0; mf < 2; ++mf)
    #pragma unroll
    for (int nf = 0; nf < 8; ++nf)
      s[mf][nf] = __builtin_amdgcn_mfma_f32_16x16x32_bf16(qa[mf], kb[nf], s[mf][nf], 0, 0, 0);
  __builtin_amdgcn_s_setprio(0);
  float rrs[2][4];
  #pragma unroll
  for (int mf = 0; mf < 2; ++mf)
    #pragma unroll
    for (int r = 0; r < 4; ++r){
      int row = wv*32 + mf*16 + 4*g + r;
      const f32x4* bp2 = (const f32x4*)&bh[((size_t)row*16 + li)*8];
      f32x4 b0 = bp2[0], b1 = bp2[1];
      float sum = 0.f;
      #pragma unroll
      for (int nf = 0; nf < 8; ++nf){
        float bb = (nf < 4) ? b0[nf] : b1[nf & 3];
        float e = EXP2(s[mf][nf][r]*KS + bb);
        s[mf][nf][r] = e;
        sum += e;
      }
      #pragma unroll
      for (int d = 1; d < 16; d <<= 1) sum += __shfl_xor(sum, d, 64);
      rrs[mf][r] = 1.0f / sum;
    }
  #pragma unroll
  for (int mf = 0; mf < 2; ++mf)
    #pragma unroll
    for (int r = 0; r < 4; ++r){
      int rl = mf*16 + 4*g + r;
      #pragma unroll
      for (int nf = 0; nf < 8; ++nf)
        pTw[rl*136 + nf*16 + li] = f2bf(s[mf][nf][r]);
    }
  __syncthreads();
  f32x4 oacc[2][2] = {};
  #pragma unroll
  for (int kk = 0; kk < 4; ++kk){
    bf16x8 pa[2];
    #pragma unroll
    for (int mf = 0; mf < 2; ++mf)
      pa[mf] = *(const bf16x8*)&pTw[(mf*16 + li)*136 + kk*32 + 8*g];
    __builtin_amdgcn_s_setprio(1);
    #pragma unroll
    for (int mf = 0; mf < 2; ++mf)
      #pragma unroll
      for (int nf = 0; nf < 2; ++nf)
        oacc[mf][nf] = __builtin_amdgcn_mfma_f32_16x16x32_bf16(pa[mf], vb[nf][kk], oacc[mf][nf], 0, 0, 0);
    __builtin_amdgcn_s_setprio(0);
  }
  ush* oL = o + (size_t)lw * L_ * C_;
  #pragma unroll
  for (int mf = 0; mf < 2; ++mf)
    #pragma unroll
    for (int r = 0; r < 4; ++r){
      int q = wv*32 + mf*16 + 4*g + r;
      #pragma unroll
      for (int nf = 0; nf < 2; ++nf)
        oL[(size_t)q*C_ + h*DIM_ + nf*16 + li] = f2bf(oacc[mf][nf][r] * rrs[mf][r]);
    }
}

// ---------------- projection, 2-phase double-buffered staging (unchanged) ----------------
__global__ __launch_bounds__(256) void k_proj(const ush* __restrict__ oIn, const ush* __restrict__ wpb,
                                              const float* __restrict__ bp, float* __restrict__ out,
                                              int nbtl, int bt0){
  int idx = blockIdx.x;
  int lo3 = idx & 7, rest = idx >> 3;
  int mt = rest & 1, hi = rest >> 1;
  int btl = hi*8 + lo3;
  const int l = btl & (L_-1), btL = btl >> 7;
  __shared__ ush lA[2*128*64];
  __shared__ ush lB[2*128*64];
  const int t = threadIdx.x;
  const int lane = t & 63, wv = t >> 6;
  const int wm = (wv >> 1)*64, wn = (wv & 1)*64;
  const int li = lane & 15, g = lane >> 4;
  f32x4 acc[4][4] = {};
  const ush* aBase = wpb + (size_t)mt*128*C_;
  const ush* bBase = oIn + ((size_t)btL*W_*L_ + l)*C_;
  const int rowOff = lane >> 3;
  const int srcCl  = (lane & 7) ^ rowOff;
  auto stage = [&](int buf, int ks){
#ifdef HAVE_GLL
    #pragma unroll
    for (int c = 0; c < 4; ++c){
      int chunk = wv*4 + c;
      int row = chunk*8 + rowOff;
      gll16(aBase + (size_t)row*C_        + ks*64 + srcCl*8, &lA[buf*8192 + chunk*512]);
      gll16(bBase + (size_t)row*(L_*C_)   + ks*64 + srcCl*8, &lB[buf*8192 + chunk*512]);
    }
#else
    #pragma unroll
    for (int j = 0; j < 4; ++j){
      int cid = j*256 + t;
      int row = cid >> 3, cl = cid & 7;
      int sw = ((cl ^ (row & 7)) << 3);
      *(bf16x8*)&lA[buf*8192 + row*64 + sw] = *(const bf16x8*)&aBase[(size_t)row*C_ + ks*64 + cl*8];
      *(bf16x8*)&lB[buf*8192 + row*64 + sw] = *(const bf16x8*)&bBase[(size_t)row*(L_*C_) + ks*64 + cl*8];
    }
#endif
  };
  stage(0, 0);
  __syncthreads();
  int cur = 0;
  for (int ks = 0; ks < 4; ++ks){
    if (ks < 3) stage(cur^1, ks+1);
    #pragma unroll
    for (int kk = 0; kk < 2; ++kk){
      bf16x8 af[4], bfr[4];
      int chunk = kk*4 + g;
      #pragma unroll
      for (int mf = 0; mf < 4; ++mf){
        int row = wm + mf*16 + li;
        af[mf] = *(const bf16x8*)&lA[cur*8192 + row*64 + ((chunk ^ (row & 7)) << 3)];
      }
      #pragma unroll
      for (int nf = 0; nf < 4; ++nf){
        int row = wn + nf*16 + li;
        bfr[nf] = *(const bf16x8*)&lB[cur*8192 + row*64 + ((chunk ^ (row & 7)) << 3)];
      }
      #pragma unroll
      for (int mf = 0; mf < 4; ++mf)
        #pragma unroll
        for (int nf = 0; nf < 4; ++nf)
          acc[mf][nf] = __builtin_amdgcn_mfma_f32_16x16x32_bf16(af[mf], bfr[nf], acc[mf][nf], 0, 0, 0);
    }
    __syncthreads();
    cur ^= 1;
  }
  #pragma unroll
  for (int mf = 0; mf < 4; ++mf){
    #pragma unroll
    for (int r = 0; r < 4; ++r){
      int c = mt*128 + wm + mf*16 + 4*g + r;
      float bias = bp[c];
      size_t rowbase = (((size_t)(bt0 + btL)*C_ + c)*H_ + l)*W_;
      #pragma unroll
      for (int nf = 0; nf < 4; ++nf){
        out[rowbase + wn + nf*16 + li] = acc[mf][nf][r] + bias;
      }
    }
  }
}

extern "C" void kernel_launch(void* const* d_in, const int* in_sizes, int n_in,
                              void* d_out, int out_size, void* d_ws, size_t ws_size,
                              hipStream_t stream){
  const float* x  = (const float*)d_in[0];
  const float* rb = (const float*)d_in[1];
  const float* wq = (const float*)d_in[2];
  const float* bq = (const float*)d_in[3];
  const float* wp = (const float*)d_in[4];
  const float* bp = (const float*)d_in[5];
  float* out = (float*)d_out;
  char* ws = (char*)d_ws;
  ush* wqb = (ush*)ws;
  ush* wpb = wqb + C3*C_;
  size_t wend = ((size_t)(C3*C_ + C_*C_)*2 + 255) & ~(size_t)255;
  float* biasE = (float*)(ws + wend);
  size_t base = (wend + (size_t)HEADS_*L_*L_*4 + 255) & ~(size_t)255;
  const size_t xT_bt  = (size_t)L_*W_*C_*2;   // 8 MiB
  const size_t o_bt   = (size_t)W_*L_*C_*2;   // 8 MiB
  const size_t per_bt = xT_bt + o_bt;
  int G = (ws_size > base) ? (int)((ws_size - base) / per_bt) : 0;
  if (G > NBT) G = NBT;
  if (G > 8)   G = 8;   // 128 MiB working set — L3-resident
  if (G < 1)   G = 1;

  k_setup<<<dim3((C3*C_ + 255)/256), dim3(256), 0, stream>>>(wq, wp, rb, wqb, wpb, biasE);

  for (int bt0 = 0; bt0 < NBT; bt0 += G){
    int gc = (NBT - bt0 < G) ? (NBT - bt0) : G;
    ush* xT  = (ush*)(ws + base);
    ush* oB  = (ush*)(ws + base + (size_t)gc*xT_bt);
    int nbtl = gc*L_;
    k_trans   <<<dim3(nbtl),      dim3(256), 0, stream>>>(x, xT, bt0);
    k_qkvattn <<<dim3(8*gc*W_),   dim3(256), 0, stream>>>(xT, wqb, bq, biasE, oB);
    k_proj    <<<dim3(2*nbtl),    dim3(256), 0, stream>>>(oB, wpb, bp, out, nbtl, bt0);
  }
}

// Round 17
// 468.808 us; speedup vs baseline: 1.6562x; 1.6562x over previous
//
#include <hip/hip_runtime.h>

#define B_ 2
#define T_ 8
#define C_ 256
#define H_ 128
#define W_ 128
#define NBT (B_*T_)
#define L_ 128
#define HEADS_ 8
#define DIM_ 32
#define C3 (3*C_)
#define SCALE_ 0.17677669529663687f
#define LOG2E_ 1.4426950408889634f
#define QSTR 104   // qkvt LDS row stride (ush): 96 cols + 8 pad (bank-spread)

typedef __bf16 bf16x8 __attribute__((ext_vector_type(8)));
typedef float f32x4 __attribute__((ext_vector_type(4)));
typedef unsigned short ush;
typedef unsigned short u16x4 __attribute__((ext_vector_type(4)));
typedef unsigned int uint_a __attribute__((may_alias));

__device__ __forceinline__ ush f2bf(float f){
  union { float f; unsigned int u; } v; v.f = f;
  unsigned int r = v.u + 0x7fffu + ((v.u >> 16) & 1u);
  return (ush)(r >> 16);
}

#if __has_builtin(__builtin_amdgcn_exp2f)
#define EXP2(x) __builtin_amdgcn_exp2f(x)
#else
#define EXP2(x) exp2f(x)
#endif

#if __has_builtin(__builtin_amdgcn_global_load_lds)
#define HAVE_GLL 1
typedef __attribute__((address_space(3))) ush lds_ush;
typedef __attribute__((address_space(1))) const ush glb_ush;
__device__ __forceinline__ void gll16(const ush* g, ush* l){
  __builtin_amdgcn_global_load_lds((glb_ush*)g, (lds_ush*)l, 16, 0, 0);
}
#endif

// ---------------- setup: weight f32->bf16 + bias*log2e (lane-contig layout) ----------------
__global__ __launch_bounds__(256) void k_setup(const float* __restrict__ wq, const float* __restrict__ wp,
                                               const float* __restrict__ rb,
                                               ush* __restrict__ wqb, ush* __restrict__ wpb,
                                               float* __restrict__ be){
  int i = blockIdx.x*256 + threadIdx.x;
  if (i < C3*C_) wqb[i] = f2bf(wq[i]);
  if (i < C_*C_) wpb[i] = f2bf(wp[i]);
  if (i < HEADS_*L_*L_){
    int col = i & (L_-1);
    int hrow = i >> 7;           // h*L + row
    int tgt = ((hrow<<4) + (col & 15))*8 + (col >> 4);
    be[tgt] = rb[i]*LOG2E_;
  }
}

// ---------------- transpose x (bt,c,l,w) -> xT[btL][l][w][c] bf16 ----------------
__global__ __launch_bounds__(256) void k_trans(const float* __restrict__ x, ush* __restrict__ xT, int bt0){
  __shared__ float tile[64*129];
  const int l   = blockIdx.x & (L_-1);
  const int btL = blockIdx.x >> 7;
  const int t = threadIdx.x;
  const float* xp = x + (size_t)(bt0 + btL)*C_*H_*W_ + (size_t)l*W_;
  ush* xo = xT + ((size_t)blockIdx.x) * W_ * C_;
  const int wI = t & (W_-1);
  const int chh = t >> 7;
  const int c2 = (t & 31)*2;
  const int wr0 = t >> 5;
  for (int cs = 0; cs < 4; ++cs){
    #pragma unroll 4
    for (int i = 0; i < 32; ++i){
      int cl = chh*32 + i;
      tile[cl*129 + wI] = xp[(size_t)(cs*64 + cl)*(H_*W_) + wI];
    }
    __syncthreads();
    #pragma unroll 4
    for (int i = 0; i < 16; ++i){
      int wr = wr0 + i*8;
      float v0 = tile[c2*129 + wr];
      float v1 = tile[(c2+1)*129 + wr];
      unsigned int pk = (unsigned int)f2bf(v0) | ((unsigned int)f2bf(v1) << 16);
      *(uint_a*)(xo + (size_t)wr*C_ + cs*64 + c2) = pk;
    }
    __syncthreads();
  }
}

// ---------------- fused QKV GEMM + attention, per (btL, w, h) ----------------
// Single-buffered lA/lB (2-barrier K-loop) + qkvt/pT overlay: 34.8 KB LDS ->
// 4 blocks/CU. NO launch_bounds waves pin (R16's pin forced VGPR=64 -> spill
// storm: FETCH 362MB, WRITE 665MB/dispatch). Natural VGPR ~120 keeps 16 waves/CU.
__global__ __launch_bounds__(256) void k_qkvattn(const ush* __restrict__ xT, const ush* __restrict__ wqb,
                                                 const float* __restrict__ bq, const float* __restrict__ biasE,
                                                 ush* __restrict__ o){
  __shared__ ush smem[17408];            // 34816 B
  int idx = blockIdx.x;
  int lo3 = idx & 7, rest = idx >> 3;
  int h = rest & 7;
  int lw = (rest >> 3)*8 + lo3;          // btL*W + w
  const int btL = lw >> 7, w = lw & (W_-1);
  const int t = threadIdx.x;
  const int lane = t & 63, wv = t >> 6;
  const int li = lane & 15, g = lane >> 4;
  ush* lA = smem;                        // GEMM: 128x64 (16384 B)
  ush* lB = smem + 8192;                 // GEMM: 96x64  (12288 B)
  ush* qkvt = smem;                      // attn: 128 x QSTR (26624 B)
  ush* pTw = smem + wv*(32*136);         // after qkvt consumed (34816 B)
  const ush* xA = xT + (size_t)btL*L_*W_*C_ + (size_t)w*C_;   // + l*(W_*C_) + c
  const int rowOff = lane >> 3;
  const int srcCl  = (lane & 7) ^ rowOff;
  f32x4 acc[2][6] = {};
  auto stage = [&](int ks){
#ifdef HAVE_GLL
    #pragma unroll
    for (int c = 0; c < 4; ++c){
      int chunk = wv*4 + c;              // 0..15
      int row = chunk*8 + rowOff;        // l: 0..127
      gll16(xA + (size_t)row*(W_*C_) + ks*64 + srcCl*8, &lA[chunk*512]);
    }
    #pragma unroll
    for (int c = 0; c < 3; ++c){
      int chunk = wv*3 + c;              // 0..11
      int row = chunk*8 + rowOff;        // 0..95
      int wr = (row >> 5)*C_ + h*DIM_ + (row & 31);
      gll16(wqb + (size_t)wr*C_ + ks*64 + srcCl*8, &lB[chunk*512]);
    }
#else
    #pragma unroll
    for (int j = 0; j < 4; ++j){
      int cid = j*256 + t;
      int row = cid >> 3, cl = cid & 7;
      int sw = ((cl ^ (row & 7)) << 3);
      *(bf16x8*)&lA[row*64 + sw] = *(const bf16x8*)&xA[(size_t)row*(W_*C_) + ks*64 + cl*8];
    }
    #pragma unroll
    for (int j = 0; j < 3; ++j){
      int cid = j*256 + t;
      int row = cid >> 3, cl = cid & 7;
      if (row < 96){
        int wr = (row >> 5)*C_ + h*DIM_ + (row & 31);
        int sw = ((cl ^ (row & 7)) << 3);
        *(bf16x8*)&lB[row*64 + sw] = *(const bf16x8*)&wqb[(size_t)wr*C_ + ks*64 + cl*8];
      }
    }
#endif
  };
  for (int ks = 0; ks < 4; ++ks){
    __syncthreads();   // previous step's lA/lB reads complete (no-op at ks=0)
    stage(ks);
    __syncthreads();   // staged data visible (barrier drains vmcnt)
    #pragma unroll
    for (int kk = 0; kk < 2; ++kk){
      bf16x8 af[2], bfr[6];
      int chunk = kk*4 + g;
      #pragma unroll
      for (int mf = 0; mf < 2; ++mf){
        int row = wv*32 + mf*16 + li;
        af[mf] = *(const bf16x8*)&lA[row*64 + ((chunk ^ (row & 7)) << 3)];
      }
      #pragma unroll
      for (int nf = 0; nf < 6; ++nf){
        int row = nf*16 + li;
        bfr[nf] = *(const bf16x8*)&lB[row*64 + ((chunk ^ (row & 7)) << 3)];
      }
      #pragma unroll
      for (int mf = 0; mf < 2; ++mf)
        #pragma unroll
        for (int nf = 0; nf < 6; ++nf)
          acc[mf][nf] = __builtin_amdgcn_mfma_f32_16x16x32_bf16(af[mf], bfr[nf], acc[mf][nf], 0, 0, 0);
    }
  }
  __syncthreads();   // final lA/lB reads done; smem free for qkvt
  // ---- epilogue: bias-add, bf16, drop into qkvt[l][0..96) ----
  float bqv[6];
  #pragma unroll
  for (int nf = 0; nf < 6; ++nf){
    int col = nf*16 + li;
    bqv[nf] = bq[(col >> 5)*C_ + h*DIM_ + (col & 31)];
  }
  #pragma unroll
  for (int mf = 0; mf < 2; ++mf)
    #pragma unroll
    for (int r = 0; r < 4; ++r){
      int m = wv*32 + mf*16 + 4*g + r;
      #pragma unroll
      for (int nf = 0; nf < 6; ++nf)
        qkvt[m*QSTR + nf*16 + li] = f2bf(acc[mf][nf][r] + bqv[nf]);
    }
  __syncthreads();
  // ---- attention (wave wv handles q-rows [wv*32, wv*32+32)) ----
  const float KS = SCALE_ * LOG2E_;
  bf16x8 kb[8];
  #pragma unroll
  for (int nf = 0; nf < 8; ++nf)
    kb[nf] = *(const bf16x8*)&qkvt[(nf*16 + li)*QSTR + DIM_ + 8*g];
  bf16x8 vb[2][4];
  #pragma unroll
  for (int nf = 0; nf < 2; ++nf)
    #pragma unroll
    for (int kk = 0; kk < 4; ++kk){
      ush tmp[8];
      #pragma unroll
      for (int j = 0; j < 8; ++j)
        tmp[j] = qkvt[(kk*32 + 8*g + j)*QSTR + 2*DIM_ + nf*16 + li];
      __builtin_memcpy(&vb[nf][kk], tmp, 16);
    }
  bf16x8 qa[2];
  #pragma unroll
  for (int mf = 0; mf < 2; ++mf)
    qa[mf] = *(const bf16x8*)&qkvt[(wv*32 + mf*16 + li)*QSTR + 8*g];
  __syncthreads();   // qkvt fully consumed into registers; pT may overwrite
  const float* bh = biasE + (size_t)h * L_ * L_;
  f32x4 s[2][8] = {};
  __builtin_amdgcn_s_setprio(1);
  #pragma unroll
  for (int mf = 0; mf < 2; ++mf)
    #pragma unroll
    for (int nf = 0; nf < 8; ++nf)
      s[mf][nf] = __builtin_amdgcn_mfma_f32_16x16x32_bf16(qa[mf], kb[nf], s[mf][nf], 0, 0, 0);
  __builtin_amdgcn_s_setprio(0);
  float rrs[2][4];
  #pragma unroll
  for (int mf = 0; mf < 2; ++mf)
    #pragma unroll
    for (int r = 0; r < 4; ++r){
      int row = wv*32 + mf*16 + 4*g + r;
      const f32x4* bp2 = (const f32x4*)&bh[((size_t)row*16 + li)*8];
      f32x4 b0 = bp2[0], b1 = bp2[1];
      float sum = 0.f;
      #pragma unroll
      for (int nf = 0; nf < 8; ++nf){
        float bb = (nf < 4) ? b0[nf] : b1[nf & 3];
        float e = EXP2(s[mf][nf][r]*KS + bb);
        s[mf][nf][r] = e;
        sum += e;
      }
      #pragma unroll
      for (int d = 1; d < 16; d <<= 1) sum += __shfl_xor(sum, d, 64);
      rrs[mf][r] = 1.0f / sum;
    }
  #pragma unroll
  for (int mf = 0; mf < 2; ++mf)
    #pragma unroll
    for (int r = 0; r < 4; ++r){
      int rl = mf*16 + 4*g + r;
      #pragma unroll
      for (int nf = 0; nf < 8; ++nf)
        pTw[rl*136 + nf*16 + li] = f2bf(s[mf][nf][r]);
    }
  __syncthreads();
  f32x4 oacc[2][2] = {};
  #pragma unroll
  for (int kk = 0; kk < 4; ++kk){
    bf16x8 pa[2];
    #pragma unroll
    for (int mf = 0; mf < 2; ++mf)
      pa[mf] = *(const bf16x8*)&pTw[(mf*16 + li)*136 + kk*32 + 8*g];
    __builtin_amdgcn_s_setprio(1);
    #pragma unroll
    for (int mf = 0; mf < 2; ++mf)
      #pragma unroll
      for (int nf = 0; nf < 2; ++nf)
        oacc[mf][nf] = __builtin_amdgcn_mfma_f32_16x16x32_bf16(pa[mf], vb[nf][kk], oacc[mf][nf], 0, 0, 0);
    __builtin_amdgcn_s_setprio(0);
  }
  ush* oL = o + (size_t)lw * L_ * C_;
  #pragma unroll
  for (int mf = 0; mf < 2; ++mf)
    #pragma unroll
    for (int r = 0; r < 4; ++r){
      int q = wv*32 + mf*16 + 4*g + r;
      #pragma unroll
      for (int nf = 0; nf < 2; ++nf)
        oL[(size_t)q*C_ + h*DIM_ + nf*16 + li] = f2bf(oacc[mf][nf][r] * rrs[mf][r]);
    }
}

// ---------------- projection, 2-phase double-buffered staging (unchanged) ----------------
__global__ __launch_bounds__(256) void k_proj(const ush* __restrict__ oIn, const ush* __restrict__ wpb,
                                              const float* __restrict__ bp, float* __restrict__ out,
                                              int nbtl, int bt0){
  int idx = blockIdx.x;
  int lo3 = idx & 7, rest = idx >> 3;
  int mt = rest & 1, hi = rest >> 1;
  int btl = hi*8 + lo3;
  const int l = btl & (L_-1), btL = btl >> 7;
  __shared__ ush lA[2*128*64];
  __shared__ ush lB[2*128*64];
  const int t = threadIdx.x;
  const int lane = t & 63, wv = t >> 6;
  const int wm = (wv >> 1)*64, wn = (wv & 1)*64;
  const int li = lane & 15, g = lane >> 4;
  f32x4 acc[4][4] = {};
  const ush* aBase = wpb + (size_t)mt*128*C_;
  const ush* bBase = oIn + ((size_t)btL*W_*L_ + l)*C_;
  const int rowOff = lane >> 3;
  const int srcCl  = (lane & 7) ^ rowOff;
  auto stage = [&](int buf, int ks){
#ifdef HAVE_GLL
    #pragma unroll
    for (int c = 0; c < 4; ++c){
      int chunk = wv*4 + c;
      int row = chunk*8 + rowOff;
      gll16(aBase + (size_t)row*C_        + ks*64 + srcCl*8, &lA[buf*8192 + chunk*512]);
      gll16(bBase + (size_t)row*(L_*C_)   + ks*64 + srcCl*8, &lB[buf*8192 + chunk*512]);
    }
#else
    #pragma unroll
    for (int j = 0; j < 4; ++j){
      int cid = j*256 + t;
      int row = cid >> 3, cl = cid & 7;
      int sw = ((cl ^ (row & 7)) << 3);
      *(bf16x8*)&lA[buf*8192 + row*64 + sw] = *(const bf16x8*)&aBase[(size_t)row*C_ + ks*64 + cl*8];
      *(bf16x8*)&lB[buf*8192 + row*64 + sw] = *(const bf16x8*)&bBase[(size_t)row*(L_*C_) + ks*64 + cl*8];
    }
#endif
  };
  stage(0, 0);
  __syncthreads();
  int cur = 0;
  for (int ks = 0; ks < 4; ++ks){
    if (ks < 3) stage(cur^1, ks+1);
    #pragma unroll
    for (int kk = 0; kk < 2; ++kk){
      bf16x8 af[4], bfr[4];
      int chunk = kk*4 + g;
      #pragma unroll
      for (int mf = 0; mf < 4; ++mf){
        int row = wm + mf*16 + li;
        af[mf] = *(const bf16x8*)&lA[cur*8192 + row*64 + ((chunk ^ (row & 7)) << 3)];
      }
      #pragma unroll
      for (int nf = 0; nf < 4; ++nf){
        int row = wn + nf*16 + li;
        bfr[nf] = *(const bf16x8*)&lB[cur*8192 + row*64 + ((chunk ^ (row & 7)) << 3)];
      }
      #pragma unroll
      for (int mf = 0; mf < 4; ++mf)
        #pragma unroll
        for (int nf = 0; nf < 4; ++nf)
          acc[mf][nf] = __builtin_amdgcn_mfma_f32_16x16x32_bf16(af[mf], bfr[nf], acc[mf][nf], 0, 0, 0);
    }
    __syncthreads();
    cur ^= 1;
  }
  #pragma unroll
  for (int mf = 0; mf < 4; ++mf){
    #pragma unroll
    for (int r = 0; r < 4; ++r){
      int c = mt*128 + wm + mf*16 + 4*g + r;
      float bias = bp[c];
      size_t rowbase = (((size_t)(bt0 + btL)*C_ + c)*H_ + l)*W_;
      #pragma unroll
      for (int nf = 0; nf < 4; ++nf){
        out[rowbase + wn + nf*16 + li] = acc[mf][nf][r] + bias;
      }
    }
  }
}

extern "C" void kernel_launch(void* const* d_in, const int* in_sizes, int n_in,
                              void* d_out, int out_size, void* d_ws, size_t ws_size,
                              hipStream_t stream){
  const float* x  = (const float*)d_in[0];
  const float* rb = (const float*)d_in[1];
  const float* wq = (const float*)d_in[2];
  const float* bq = (const float*)d_in[3];
  const float* wp = (const float*)d_in[4];
  const float* bp = (const float*)d_in[5];
  float* out = (float*)d_out;
  char* ws = (char*)d_ws;
  ush* wqb = (ush*)ws;
  ush* wpb = wqb + C3*C_;
  size_t wend = ((size_t)(C3*C_ + C_*C_)*2 + 255) & ~(size_t)255;
  float* biasE = (float*)(ws + wend);
  size_t base = (wend + (size_t)HEADS_*L_*L_*4 + 255) & ~(size_t)255;
  const size_t xT_bt  = (size_t)L_*W_*C_*2;   // 8 MiB
  const size_t o_bt   = (size_t)W_*L_*C_*2;   // 8 MiB
  const size_t per_bt = xT_bt + o_bt;
  int G = (ws_size > base) ? (int)((ws_size - base) / per_bt) : 0;
  if (G > NBT) G = NBT;
  if (G > 8)   G = 8;   // 128 MiB working set — L3-resident
  if (G < 1)   G = 1;

  k_setup<<<dim3((C3*C_ + 255)/256), dim3(256), 0, stream>>>(wq, wp, rb, wqb, wpb, biasE);

  for (int bt0 = 0; bt0 < NBT; bt0 += G){
    int gc = (NBT - bt0 < G) ? (NBT - bt0) : G;
    ush* xT  = (ush*)(ws + base);
    ush* oB  = (ush*)(ws + base + (size_t)gc*xT_bt);
    int nbtl = gc*L_;
    k_trans   <<<dim3(nbtl),      dim3(256), 0, stream>>>(x, xT, bt0);
    k_qkvattn <<<dim3(8*gc*W_),   dim3(256), 0, stream>>>(xT, wqb, bq, biasE, oB);
    k_proj    <<<dim3(2*nbtl),    dim3(256), 0, stream>>>(oB, wpb, bp, out, nbtl, bt0);
  }
}

// Round 18
// 438.506 us; speedup vs baseline: 1.7707x; 1.0691x over previous
//
#include <hip/hip_runtime.h>

#define B_ 2
#define T_ 8
#define C_ 256
#define H_ 128
#define W_ 128
#define NBT (B_*T_)
#define L_ 128
#define HEADS_ 8
#define DIM_ 32
#define C3 (3*C_)
#define SCALE_ 0.17677669529663687f
#define LOG2E_ 1.4426950408889634f
#define QSTR 104   // qkvt LDS row stride (ush)

typedef __bf16 bf16x8 __attribute__((ext_vector_type(8)));
typedef float f32x4 __attribute__((ext_vector_type(4)));
typedef unsigned short ush;
typedef unsigned short u16x4 __attribute__((ext_vector_type(4)));
typedef unsigned int uint_a __attribute__((may_alias));

__device__ __forceinline__ ush f2bf(float f){
  union { float f; unsigned int u; } v; v.f = f;
  unsigned int r = v.u + 0x7fffu + ((v.u >> 16) & 1u);
  return (ush)(r >> 16);
}

#if __has_builtin(__builtin_amdgcn_exp2f)
#define EXP2(x) __builtin_amdgcn_exp2f(x)
#else
#define EXP2(x) exp2f(x)
#endif

#if __has_builtin(__builtin_amdgcn_global_load_lds)
#define HAVE_GLL 1
typedef __attribute__((address_space(3))) ush lds_ush;
typedef __attribute__((address_space(1))) const ush glb_ush;
__device__ __forceinline__ void gll16(const ush* g, ush* l){
  __builtin_amdgcn_global_load_lds((glb_ush*)g, (lds_ush*)l, 16, 0, 0);
}
#endif

// ---------------- setup: weight f32->bf16 + bias*log2e (lane-contig layout) ----------------
__global__ __launch_bounds__(256) void k_setup(const float* __restrict__ wq, const float* __restrict__ wp,
                                               const float* __restrict__ rb,
                                               ush* __restrict__ wqb, ush* __restrict__ wpb,
                                               float* __restrict__ be){
  int i = blockIdx.x*256 + threadIdx.x;
  if (i < C3*C_) wqb[i] = f2bf(wq[i]);
  if (i < C_*C_) wpb[i] = f2bf(wp[i]);
  if (i < HEADS_*L_*L_){
    int col = i & (L_-1);
    int hrow = i >> 7;           // h*L + row
    int tgt = ((hrow<<4) + (col & 15))*8 + (col >> 4);
    be[tgt] = rb[i]*LOG2E_;
  }
}

// ---------------- transpose x (bt,c,l,w) -> xT[btL][l][w][c] bf16 ----------------
__global__ __launch_bounds__(256) void k_trans(const float* __restrict__ x, ush* __restrict__ xT, int bt0){
  __shared__ float tile[64*129];
  const int l   = blockIdx.x & (L_-1);
  const int btL = blockIdx.x >> 7;
  const int t = threadIdx.x;
  const float* xp = x + (size_t)(bt0 + btL)*C_*H_*W_ + (size_t)l*W_;
  ush* xo = xT + ((size_t)blockIdx.x) * W_ * C_;
  const int wI = t & (W_-1);
  const int chh = t >> 7;
  const int c2 = (t & 31)*2;
  const int wr0 = t >> 5;
  for (int cs = 0; cs < 4; ++cs){
    #pragma unroll 4
    for (int i = 0; i < 32; ++i){
      int cl = chh*32 + i;
      tile[cl*129 + wI] = xp[(size_t)(cs*64 + cl)*(H_*W_) + wI];
    }
    __syncthreads();
    #pragma unroll 4
    for (int i = 0; i < 16; ++i){
      int wr = wr0 + i*8;
      float v0 = tile[c2*129 + wr];
      float v1 = tile[(c2+1)*129 + wr];
      unsigned int pk = (unsigned int)f2bf(v0) | ((unsigned int)f2bf(v1) << 16);
      *(uint_a*)(xo + (size_t)wr*C_ + cs*64 + c2) = pk;
    }
    __syncthreads();
  }
}

// ---------------- fused QKV GEMM + attention, per (btL, w, h) ----------------
// R14's dbuf GEMM (best measured). Attn delta vs R14: V written TRANSPOSED to
// vT[d][key] in the epilogue (same writes, same bits), so vb loads are 8x
// ds_read_b128 instead of 64x scalar ds_read_u16. pT overlays qkvt+vT after
// the barrier-guarded register loads (R15/R17-proven overlay).
__global__ __launch_bounds__(256) void k_qkvattn(const ush* __restrict__ xT, const ush* __restrict__ wqb,
                                                 const float* __restrict__ bq, const float* __restrict__ biasE,
                                                 ush* __restrict__ o){
  __shared__ ush smem[28672];            // 57344 B
  int idx = blockIdx.x;
  int lo3 = idx & 7, rest = idx >> 3;
  int h = rest & 7;
  int lw = (rest >> 3)*8 + lo3;          // btL*W + w
  const int btL = lw >> 7, w = lw & (W_-1);
  const int t = threadIdx.x;
  const int lane = t & 63, wv = t >> 6;
  const int li = lane & 15, g = lane >> 4;
  ush* lA = smem;                        // GEMM: 2 x 128x64 (32768 B)
  ush* lB = smem + 16384;                // GEMM: 2 x 96x64  (24576 B)
  ush* qkvt = smem;                      // attn: 128 x QSTR, Q|K cols 0..63
  ush* vT   = smem + 128*QSTR;           // attn: 32 x 136 (V transposed)
  ush* pTw  = smem + wv*(32*136);        // overlay after register loads
  const ush* xA = xT + (size_t)btL*L_*W_*C_ + (size_t)w*C_;   // + l*(W_*C_) + c
  const int rowOff = lane >> 3;
  const int srcCl  = (lane & 7) ^ rowOff;
  f32x4 acc[2][6] = {};
  auto stage = [&](int buf, int ks){
#ifdef HAVE_GLL
    #pragma unroll
    for (int c = 0; c < 4; ++c){
      int chunk = wv*4 + c;              // 0..15
      int row = chunk*8 + rowOff;        // l: 0..127
      gll16(xA + (size_t)row*(W_*C_) + ks*64 + srcCl*8, &lA[buf*8192 + chunk*512]);
    }
    #pragma unroll
    for (int c = 0; c < 3; ++c){
      int chunk = wv*3 + c;              // 0..11
      int row = chunk*8 + rowOff;        // 0..95
      int wr = (row >> 5)*C_ + h*DIM_ + (row & 31);
      gll16(wqb + (size_t)wr*C_ + ks*64 + srcCl*8, &lB[buf*6144 + chunk*512]);
    }
#else
    #pragma unroll
    for (int j = 0; j < 4; ++j){
      int cid = j*256 + t;
      int row = cid >> 3, cl = cid & 7;
      int sw = ((cl ^ (row & 7)) << 3);
      *(bf16x8*)&lA[buf*8192 + row*64 + sw] = *(const bf16x8*)&xA[(size_t)row*(W_*C_) + ks*64 + cl*8];
    }
    #pragma unroll
    for (int j = 0; j < 3; ++j){
      int cid = j*256 + t;
      int row = cid >> 3, cl = cid & 7;
      if (row < 96){
        int wr = (row >> 5)*C_ + h*DIM_ + (row & 31);
        int sw = ((cl ^ (row & 7)) << 3);
        *(bf16x8*)&lB[buf*6144 + row*64 + sw] = *(const bf16x8*)&wqb[(size_t)wr*C_ + ks*64 + cl*8];
      }
    }
#endif
  };
  stage(0, 0);
  __syncthreads();
  int cur = 0;
  for (int ks = 0; ks < 4; ++ks){
    if (ks < 3) stage(cur^1, ks+1);
    #pragma unroll
    for (int kk = 0; kk < 2; ++kk){
      bf16x8 af[2], bfr[6];
      int chunk = kk*4 + g;
      #pragma unroll
      for (int mf = 0; mf < 2; ++mf){
        int row = wv*32 + mf*16 + li;
        af[mf] = *(const bf16x8*)&lA[cur*8192 + row*64 + ((chunk ^ (row & 7)) << 3)];
      }
      #pragma unroll
      for (int nf = 0; nf < 6; ++nf){
        int row = nf*16 + li;
        bfr[nf] = *(const bf16x8*)&lB[cur*6144 + row*64 + ((chunk ^ (row & 7)) << 3)];
      }
      #pragma unroll
      for (int mf = 0; mf < 2; ++mf)
        #pragma unroll
        for (int nf = 0; nf < 6; ++nf)
          acc[mf][nf] = __builtin_amdgcn_mfma_f32_16x16x32_bf16(af[mf], bfr[nf], acc[mf][nf], 0, 0, 0);
    }
    __syncthreads();   // covers staged visibility + last reads before reuse
    cur ^= 1;
  }
  // ---- epilogue: bias-add, bf16; Q|K -> qkvt rows, V -> vT transposed ----
  float bqv[6];
  #pragma unroll
  for (int nf = 0; nf < 6; ++nf){
    int col = nf*16 + li;
    bqv[nf] = bq[(col >> 5)*C_ + h*DIM_ + (col & 31)];
  }
  #pragma unroll
  for (int mf = 0; mf < 2; ++mf)
    #pragma unroll
    for (int r = 0; r < 4; ++r){
      int m = wv*32 + mf*16 + 4*g + r;
      #pragma unroll
      for (int nf = 0; nf < 4; ++nf)
        qkvt[m*QSTR + nf*16 + li] = f2bf(acc[mf][nf][r] + bqv[nf]);
      #pragma unroll
      for (int nf = 4; nf < 6; ++nf){
        int d = (nf - 4)*16 + li;
        vT[d*136 + m] = f2bf(acc[mf][nf][r] + bqv[nf]);
      }
    }
  __syncthreads();
  // ---- attention (wave wv handles q-rows [wv*32, wv*32+32)) ----
  const float KS = SCALE_ * LOG2E_;
  bf16x8 kb[8];
  #pragma unroll
  for (int nf = 0; nf < 8; ++nf)
    kb[nf] = *(const bf16x8*)&qkvt[(nf*16 + li)*QSTR + DIM_ + 8*g];
  bf16x8 vb[2][4];
  #pragma unroll
  for (int nf = 0; nf < 2; ++nf)
    #pragma unroll
    for (int kk = 0; kk < 4; ++kk)
      vb[nf][kk] = *(const bf16x8*)&vT[(nf*16 + li)*136 + kk*32 + 8*g];
  bf16x8 qa[2];
  #pragma unroll
  for (int mf = 0; mf < 2; ++mf)
    qa[mf] = *(const bf16x8*)&qkvt[(wv*32 + mf*16 + li)*QSTR + 8*g];
  __syncthreads();   // qkvt/vT fully in registers; pT may overwrite
  const float* bh = biasE + (size_t)h * L_ * L_;
  f32x4 s[2][8] = {};
  __builtin_amdgcn_s_setprio(1);
  #pragma unroll
  for (int mf = 0; mf < 2; ++mf)
    #pragma unroll
    for (int nf = 0; nf < 8; ++nf)
      s[mf][nf] = __builtin_amdgcn_mfma_f32_16x16x32_bf16(qa[mf], kb[nf], s[mf][nf], 0, 0, 0);
  __builtin_amdgcn_s_setprio(0);
  float rrs[2][4];
  #pragma unroll
  for (int mf = 0; mf < 2; ++mf)
    #pragma unroll
    for (int r = 0; r < 4; ++r){
      int row = wv*32 + mf*16 + 4*g + r;
      const f32x4* bp2 = (const f32x4*)&bh[((size_t)row*16 + li)*8];
      f32x4 b0 = bp2[0], b1 = bp2[1];
      float sum = 0.f;
      #pragma unroll
      for (int nf = 0; nf < 8; ++nf){
        float bb = (nf < 4) ? b0[nf] : b1[nf & 3];
        float e = EXP2(s[mf][nf][r]*KS + bb);
        s[mf][nf][r] = e;
        sum += e;
      }
      #pragma unroll
      for (int d = 1; d < 16; d <<= 1) sum += __shfl_xor(sum, d, 64);
      rrs[mf][r] = 1.0f / sum;
    }
  #pragma unroll
  for (int mf = 0; mf < 2; ++mf)
    #pragma unroll
    for (int r = 0; r < 4; ++r){
      int rl = mf*16 + 4*g + r;
      #pragma unroll
      for (int nf = 0; nf < 8; ++nf)
        pTw[rl*136 + nf*16 + li] = f2bf(s[mf][nf][r]);
    }
  __syncthreads();
  f32x4 oacc[2][2] = {};
  #pragma unroll
  for (int kk = 0; kk < 4; ++kk){
    bf16x8 pa[2];
    #pragma unroll
    for (int mf = 0; mf < 2; ++mf)
      pa[mf] = *(const bf16x8*)&pTw[(mf*16 + li)*136 + kk*32 + 8*g];
    __builtin_amdgcn_s_setprio(1);
    #pragma unroll
    for (int mf = 0; mf < 2; ++mf)
      #pragma unroll
      for (int nf = 0; nf < 2; ++nf)
        oacc[mf][nf] = __builtin_amdgcn_mfma_f32_16x16x32_bf16(pa[mf], vb[nf][kk], oacc[mf][nf], 0, 0, 0);
    __builtin_amdgcn_s_setprio(0);
  }
  ush* oL = o + (size_t)lw * L_ * C_;
  #pragma unroll
  for (int mf = 0; mf < 2; ++mf)
    #pragma unroll
    for (int r = 0; r < 4; ++r){
      int q = wv*32 + mf*16 + 4*g + r;
      #pragma unroll
      for (int nf = 0; nf < 2; ++nf)
        oL[(size_t)q*C_ + h*DIM_ + nf*16 + li] = f2bf(oacc[mf][nf][r] * rrs[mf][r]);
    }
}

// ---------------- projection, 2-phase double-buffered staging (unchanged) ----------------
__global__ __launch_bounds__(256) void k_proj(const ush* __restrict__ oIn, const ush* __restrict__ wpb,
                                              const float* __restrict__ bp, float* __restrict__ out,
                                              int nbtl, int bt0){
  int idx = blockIdx.x;
  int lo3 = idx & 7, rest = idx >> 3;
  int mt = rest & 1, hi = rest >> 1;
  int btl = hi*8 + lo3;
  const int l = btl & (L_-1), btL = btl >> 7;
  __shared__ ush lA[2*128*64];
  __shared__ ush lB[2*128*64];
  const int t = threadIdx.x;
  const int lane = t & 63, wv = t >> 6;
  const int wm = (wv >> 1)*64, wn = (wv & 1)*64;
  const int li = lane & 15, g = lane >> 4;
  f32x4 acc[4][4] = {};
  const ush* aBase = wpb + (size_t)mt*128*C_;
  const ush* bBase = oIn + ((size_t)btL*W_*L_ + l)*C_;
  const int rowOff = lane >> 3;
  const int srcCl  = (lane & 7) ^ rowOff;
  auto stage = [&](int buf, int ks){
#ifdef HAVE_GLL
    #pragma unroll
    for (int c = 0; c < 4; ++c){
      int chunk = wv*4 + c;
      int row = chunk*8 + rowOff;
      gll16(aBase + (size_t)row*C_        + ks*64 + srcCl*8, &lA[buf*8192 + chunk*512]);
      gll16(bBase + (size_t)row*(L_*C_)   + ks*64 + srcCl*8, &lB[buf*8192 + chunk*512]);
    }
#else
    #pragma unroll
    for (int j = 0; j < 4; ++j){
      int cid = j*256 + t;
      int row = cid >> 3, cl = cid & 7;
      int sw = ((cl ^ (row & 7)) << 3);
      *(bf16x8*)&lA[buf*8192 + row*64 + sw] = *(const bf16x8*)&aBase[(size_t)row*C_ + ks*64 + cl*8];
      *(bf16x8*)&lB[buf*8192 + row*64 + sw] = *(const bf16x8*)&bBase[(size_t)row*(L_*C_) + ks*64 + cl*8];
    }
#endif
  };
  stage(0, 0);
  __syncthreads();
  int cur = 0;
  for (int ks = 0; ks < 4; ++ks){
    if (ks < 3) stage(cur^1, ks+1);
    #pragma unroll
    for (int kk = 0; kk < 2; ++kk){
      bf16x8 af[4], bfr[4];
      int chunk = kk*4 + g;
      #pragma unroll
      for (int mf = 0; mf < 4; ++mf){
        int row = wm + mf*16 + li;
        af[mf] = *(const bf16x8*)&lA[cur*8192 + row*64 + ((chunk ^ (row & 7)) << 3)];
      }
      #pragma unroll
      for (int nf = 0; nf < 4; ++nf){
        int row = wn + nf*16 + li;
        bfr[nf] = *(const bf16x8*)&lB[cur*8192 + row*64 + ((chunk ^ (row & 7)) << 3)];
      }
      #pragma unroll
      for (int mf = 0; mf < 4; ++mf)
        #pragma unroll
        for (int nf = 0; nf < 4; ++nf)
          acc[mf][nf] = __builtin_amdgcn_mfma_f32_16x16x32_bf16(af[mf], bfr[nf], acc[mf][nf], 0, 0, 0);
    }
    __syncthreads();
    cur ^= 1;
  }
  #pragma unroll
  for (int mf = 0; mf < 4; ++mf){
    #pragma unroll
    for (int r = 0; r < 4; ++r){
      int c = mt*128 + wm + mf*16 + 4*g + r;
      float bias = bp[c];
      size_t rowbase = (((size_t)(bt0 + btL)*C_ + c)*H_ + l)*W_;
      #pragma unroll
      for (int nf = 0; nf < 4; ++nf){
        out[rowbase + wn + nf*16 + li] = acc[mf][nf][r] + bias;
      }
    }
  }
}

extern "C" void kernel_launch(void* const* d_in, const int* in_sizes, int n_in,
                              void* d_out, int out_size, void* d_ws, size_t ws_size,
                              hipStream_t stream){
  const float* x  = (const float*)d_in[0];
  const float* rb = (const float*)d_in[1];
  const float* wq = (const float*)d_in[2];
  const float* bq = (const float*)d_in[3];
  const float* wp = (const float*)d_in[4];
  const float* bp = (const float*)d_in[5];
  float* out = (float*)d_out;
  char* ws = (char*)d_ws;
  ush* wqb = (ush*)ws;
  ush* wpb = wqb + C3*C_;
  size_t wend = ((size_t)(C3*C_ + C_*C_)*2 + 255) & ~(size_t)255;
  float* biasE = (float*)(ws + wend);
  size_t base = (wend + (size_t)HEADS_*L_*L_*4 + 255) & ~(size_t)255;
  const size_t xT_bt  = (size_t)L_*W_*C_*2;   // 8 MiB
  const size_t o_bt   = (size_t)W_*L_*C_*2;   // 8 MiB
  const size_t per_bt = xT_bt + o_bt;
  int G = (ws_size > base) ? (int)((ws_size - base) / per_bt) : 0;
  if (G > NBT) G = NBT;
  if (G > 8)   G = 8;   // 128 MiB working set — L3-resident
  if (G < 1)   G = 1;

  k_setup<<<dim3((C3*C_ + 255)/256), dim3(256), 0, stream>>>(wq, wp, rb, wqb, wpb, biasE);

  for (int bt0 = 0; bt0 < NBT; bt0 += G){
    int gc = (NBT - bt0 < G) ? (NBT - bt0) : G;
    ush* xT  = (ush*)(ws + base);
    ush* oB  = (ush*)(ws + base + (size_t)gc*xT_bt);
    int nbtl = gc*L_;
    k_trans   <<<dim3(nbtl),      dim3(256), 0, stream>>>(x, xT, bt0);
    k_qkvattn <<<dim3(8*gc*W_),   dim3(256), 0, stream>>>(xT, wqb, bq, biasE, oB);
    k_proj    <<<dim3(2*nbtl),    dim3(256), 0, stream>>>(oB, wpb, bp, out, nbtl, bt0);
  }
}